// Round 1
// 813.981 us; speedup vs baseline: 1.0068x; 1.0068x over previous
//
#include <hip/hip_runtime.h>

// DMPNN encoder, MI355X bf16-MFMA, round 7: software-pipelined persistent k_msg.
//
// Pipeline (pos-space, alternating e-/f-layout; identities:
//   fidx[p]=rev[eidx[p]], sidx[p]=dst[eidx[p]]=src[fidx[p]] (sorted),
//   pidx[p]=posOf[fidx[p]] fix-point-free involution):
//   k_init : staged LDS GEMM, write e-layout @pidx[p]
//   segsum1: sequential (e-layout)
//   k_msg1 : tmp0[sidx[p]] + h0@p -> h1 f-layout @p      (all-stream)
//   segsum2: gather rows pidx[seg]
//   k_msg2 : tmp1[sidx[p]] + h1@pidx[p] -> h2 e-layout @pidx[p]
//   segsum3: sequential
//   k_out  : stream
//
// k_msg round-7 change: rocprof showed MfmaUtil 6%, VALUBusy 22%, HBM 23%,
// Occupancy 21% -> latency-bound serial chain (idx load -> gather -> VALU
// repack -> MFMA -> store) with loads in flight only ~30% of wave lifetime.
// Now: persistent waves (grid 512 = 2 blocks/CU), 1-deep software pipeline:
// tile t+1's indices+gathers issued into freed raw regs while tile t runs
// convert/MFMA/store. In-place safe: row ownership is a bijection, so a
// wave's prefetch rows are never another wave's store rows. VALU chain cut
// ~45% via v_cvt_pk_bf16_f32 (sub in f32 on <<16/&0xffff0000 bit views,
// single-instruction RNE pack).
//
// Weight channel permutation c(p) = (p&64) + 2*(p&15) + ((p>>4)&1) + 32*((p>>5)&1)
// == 32*(p>>5) + 2*(p&15) + ((p>>4)&1) for p<128: lane ln's j-pair (2a,2a+1)
// holds adjacent channels 32a+2ln, 32a+2ln+1 -> packed u32 stores.

typedef unsigned int u32;
typedef unsigned short u16;
using bf16x8 = __attribute__((ext_vector_type(8))) __bf16;
using f32x4  = __attribute__((ext_vector_type(4))) float;

#define NN 50000
#define NP 400000
#define NE 800000
#define AF 133
#define HID 128
#define ATU 68      // atomBf row stride in u32
#define KPU1 84     // k_init LDS stride; 80 data u32 = 160 cols = 5 chunks
#define KC1 5
#define WHU 64      // Wh packed row stride (u32) = 256 B rows
#define KPU3 148    // k_out stride; 144 data u32 = 288 cols = 9 chunks
#define KC3 9
#define NCH 196     // scan chunks of 256 covering NN

__device__ __forceinline__ u16 f2bf(float f) {
    union { float f; u32 u; } x; x.f = f;
    u32 r = x.u + 0x7fffu + ((x.u >> 16) & 1u);   // RNE
    return (u16)(r >> 16);
}
__device__ __forceinline__ float bf2f(u16 b) {
    union { u32 u; float f; } x; x.u = ((u32)b) << 16;
    return x.f;
}
__device__ __forceinline__ float lo16(u32 v) { return bf2f((u16)v); }
__device__ __forceinline__ float hi16(u32 v) { return bf2f((u16)(v >> 16)); }
__device__ __forceinline__ u32 pack2(float a, float b) {
    return (u32)f2bf(a) | ((u32)f2bf(b) << 16);
}
__device__ __forceinline__ float relu(float v) { return v > 0.f ? v : 0.f; }

// single-instruction RNE pack of two f32 -> packed bf16x2 (no builtin on gfx950)
__device__ __forceinline__ u32 cvt_pk_bf16(float lo, float hi) {
    u32 r;
    asm("v_cvt_pk_bf16_f32 %0, %1, %2" : "=v"(r) : "v"(lo), "v"(hi));
    return r;
}
__device__ __forceinline__ float bfLO(u32 v) {
    union { u32 u; float f; } x; x.u = v << 16; return x.f;
}
__device__ __forceinline__ float bfHI(u32 v) {
    union { u32 u; float f; } x; x.u = v & 0xffff0000u; return x.f;
}
// (t - h) per packed bf16 pair: exact f32 subtract of bf16 values, RNE pack
__device__ __forceinline__ u32 sub2_pk(u32 t, u32 h) {
    return cvt_pk_bf16(bfLO(t) - bfLO(h), bfHI(t) - bfHI(h));
}
__device__ __forceinline__ u32 relu2_pk(float a, float b) {
    return cvt_pk_bf16(a > 0.f ? a : 0.f, b > 0.f ? b : 0.f);
}

union frag_cast { uint4 u; bf16x8 v; };

// ---------------- precompute kernels ----------------

__global__ void cvt_atom(const float* __restrict__ atom, u32* __restrict__ out) {
    int total = NN * ATU;
    for (int i = blockIdx.x * blockDim.x + threadIdx.x; i < total; i += gridDim.x * blockDim.x) {
        int n = i / ATU;
        int cu = i - n * ATU;
        int k = 2 * cu;
        float f0 = (k < AF) ? atom[n * AF + k] : 0.f;
        float f1 = (k + 1 < AF) ? atom[n * AF + k + 1] : 0.f;
        out[i] = pack2(f0, f1);
    }
}

__device__ __forceinline__ float wcol(const float* W, int n, int Kw, int len1, int off2, int len2, int k) {
    if (k < len1) return W[n * Kw + k];
    int j = k - off2;
    if (j >= 0 && j < len2) return W[n * Kw + len1 + j];
    return 0.f;
}
// Wp row p <- actual channel c(p) (output-channel permutation for packed stores)
__global__ void cvt_w(const float* __restrict__ W, u32* __restrict__ out,
                      int Kw, int KpU, int len1, int off2, int len2) {
    int total = 128 * KpU;
    for (int i = blockIdx.x * blockDim.x + threadIdx.x; i < total; i += gridDim.x * blockDim.x) {
        int p = i / KpU;
        int cu = i - p * KpU;
        int t = p & 63;
        int c = (p & 64) + 2 * (t & 15) + ((t >> 4) & 1) + 32 * ((t >> 5) & 1);
        int k = 2 * cu;
        out[i] = pack2(wcol(W, c, Kw, len1, off2, len2, k),
                       wcol(W, c, Kw, len1, off2, len2, k + 1));
    }
}

// ---------------- CSR build ----------------

__global__ void hist(const int* __restrict__ dst, int* __restrict__ cnt) {
    for (int e = blockIdx.x * blockDim.x + threadIdx.x; e < NE; e += gridDim.x * blockDim.x)
        atomicAdd(&cnt[dst[e]], 1);
}

__global__ void scan1(const int* __restrict__ cnt, int* __restrict__ lexc, int* __restrict__ chunkSum) {
    __shared__ int s[256];
    int t = threadIdx.x, idx = blockIdx.x * 256 + t;
    int v = (idx < NN) ? cnt[idx] : 0;
    s[t] = v; __syncthreads();
    for (int off = 1; off < 256; off <<= 1) {
        int x = (t >= off) ? s[t - off] : 0;
        __syncthreads();
        s[t] += x;
        __syncthreads();
    }
    if (idx < NN) lexc[idx] = s[t] - v;
    if (t == 255) chunkSum[blockIdx.x] = s[255];
}

__global__ void scan2(const int* __restrict__ chunkSum, int* __restrict__ chunkOff) {
    __shared__ int s[256];
    int t = threadIdx.x;
    int v = (t < NCH) ? chunkSum[t] : 0;
    s[t] = v; __syncthreads();
    for (int off = 1; off < 256; off <<= 1) {
        int x = (t >= off) ? s[t - off] : 0;
        __syncthreads();
        s[t] += x;
        __syncthreads();
    }
    if (t < NCH) chunkOff[t] = s[t] - v;
}

__global__ void scan3(const int* __restrict__ lexc, const int* __restrict__ chunkOff,
                      int* __restrict__ rowptr, int* __restrict__ cursor) {
    int idx = blockIdx.x * 256 + threadIdx.x;
    if (idx < NN) {
        int v = lexc[idx] + chunkOff[blockIdx.x];
        rowptr[idx] = v;
        cursor[idx] = v;
    }
    if (idx == 0) rowptr[NN] = NE;
}

__global__ void scatter(const int* __restrict__ dst, const int* __restrict__ rev,
                        int* __restrict__ cursor, int* __restrict__ fidx,
                        int* __restrict__ sidx, int* __restrict__ posOf) {
    for (int e = blockIdx.x * blockDim.x + threadIdx.x; e < NE; e += gridDim.x * blockDim.x) {
        int d = dst[e];
        int pos = atomicAdd(&cursor[d], 1);
        fidx[pos] = rev[e];
        sidx[pos] = d;        // = src[fidx[pos]], nondecreasing over pos
        posOf[e] = pos;
    }
}

__global__ void pidx_build(const int* __restrict__ fidx, const int* __restrict__ posOf,
                           int* __restrict__ pidx) {
    for (int p = blockIdx.x * blockDim.x + threadIdx.x; p < NE; p += gridDim.x * blockDim.x)
        pidx[p] = posOf[fidx[p]];
}

// ---------------- segment sum ----------------
// one wave per node; chunk = 4 rows, lane l -> row (l>>4), uint4 col group (l&15).
template<bool G>
__global__ __launch_bounds__(256)
void segsum_t(const int* __restrict__ rowptr, const int* __restrict__ gat,
              const u32* __restrict__ h, u32* __restrict__ tmp) {
    const int lane = threadIdx.x & 63;
    const int wv = threadIdx.x >> 6;
    const int rsel = lane >> 4;
    const int cg = lane & 15;
    const int nwaves = gridDim.x * 4;
    for (int n = blockIdx.x * 4 + wv; n < NN; n += nwaves) {
        int beg = rowptr[n], end = rowptr[n + 1];
        float a0 = 0, a1 = 0, a2 = 0, a3 = 0, a4 = 0, a5 = 0, a6 = 0, a7 = 0;
        int i = beg;
        for (; i + 8 <= end; i += 8) {
            int rA = G ? gat[i + rsel] : (i + rsel);
            int rB = G ? gat[i + 4 + rsel] : (i + 4 + rsel);
            uint4 hA = *(const uint4*)(h + (size_t)rA * 64 + 4 * cg);
            uint4 hB = *(const uint4*)(h + (size_t)rB * 64 + 4 * cg);
            a0 += lo16(hA.x) + lo16(hB.x); a1 += hi16(hA.x) + hi16(hB.x);
            a2 += lo16(hA.y) + lo16(hB.y); a3 += hi16(hA.y) + hi16(hB.y);
            a4 += lo16(hA.z) + lo16(hB.z); a5 += hi16(hA.z) + hi16(hB.z);
            a6 += lo16(hA.w) + lo16(hB.w); a7 += hi16(hA.w) + hi16(hB.w);
        }
        for (; i < end; i += 4) {
            if (i + rsel < end) {
                int rA = G ? gat[i + rsel] : (i + rsel);
                uint4 hA = *(const uint4*)(h + (size_t)rA * 64 + 4 * cg);
                a0 += lo16(hA.x); a1 += hi16(hA.x);
                a2 += lo16(hA.y); a3 += hi16(hA.y);
                a4 += lo16(hA.z); a5 += hi16(hA.z);
                a6 += lo16(hA.w); a7 += hi16(hA.w);
            }
        }
        a0 += __shfl_xor(a0, 16); a0 += __shfl_xor(a0, 32);
        a1 += __shfl_xor(a1, 16); a1 += __shfl_xor(a1, 32);
        a2 += __shfl_xor(a2, 16); a2 += __shfl_xor(a2, 32);
        a3 += __shfl_xor(a3, 16); a3 += __shfl_xor(a3, 32);
        a4 += __shfl_xor(a4, 16); a4 += __shfl_xor(a4, 32);
        a5 += __shfl_xor(a5, 16); a5 += __shfl_xor(a5, 32);
        a6 += __shfl_xor(a6, 16); a6 += __shfl_xor(a6, 32);
        a7 += __shfl_xor(a7, 16); a7 += __shfl_xor(a7, 32);
        if (rsel == 0) {
            uint4 o;
            o.x = pack2(a0, a1); o.y = pack2(a2, a3);
            o.z = pack2(a4, a5); o.w = pack2(a6, a7);
            *(uint4*)(tmp + (size_t)n * 64 + 4 * cg) = o;
        }
    }
}

// ---------------- k_init: pos-sequential 128-row tiles, LDS-staged ----------------
// writes e-layout: h0(fidx[p]) -> row pidx[p]
__global__ __launch_bounds__(256, 3)
void k_init(const u32* __restrict__ atomBf, const float* __restrict__ bond,
            const int* __restrict__ fidx, const int* __restrict__ sidx,
            const int* __restrict__ pidx, const u32* __restrict__ Wp,
            u32* __restrict__ hout)
{
    __shared__ u32 As[128 * KPU1];   // 43008 B -> 3 blocks/CU
    const int tid = threadIdx.x;
    const int lane = tid & 63;
    const int wv = tid >> 6;
    const int ln = lane & 15;
    const int q  = lane >> 4;
    const int rowBase = 64 * (wv >> 1);
    const int cbU = 32 * (wv & 1);
    const int ntiles = NE / 128;

    const int srow = tid >> 1;
    const int half = tid & 1;

    for (int tile = blockIdx.x; tile < ntiles; tile += gridDim.x) {
        const int e0 = tile * 128;
        {
            int p = e0 + srow;
            const u32* ap = atomBf + (size_t)sidx[p] * ATU;
            u32* dr = As + srow * KPU1;
            if (half == 0) {
                #pragma unroll
                for (int j = 0; j < 10; ++j)
                    *(uint4*)(dr + 4 * j) = *(const uint4*)(ap + 4 * j);
            } else {
                #pragma unroll
                for (int j = 10; j < 17; ++j)
                    *(uint4*)(dr + 4 * j) = *(const uint4*)(ap + 4 * j);
                const float* bp = bond + (size_t)fidx[p] * 14;
                float2 b0 = *(const float2*)(bp + 0);
                float2 b1 = *(const float2*)(bp + 2);
                float2 b2 = *(const float2*)(bp + 4);
                float2 b3 = *(const float2*)(bp + 6);
                float2 b4 = *(const float2*)(bp + 8);
                float2 b5 = *(const float2*)(bp + 10);
                float2 b6 = *(const float2*)(bp + 12);
                *(uint4*)(dr + 68) = make_uint4(pack2(b0.x, b0.y), pack2(b1.x, b1.y),
                                                pack2(b2.x, b2.y), pack2(b3.x, b3.y));
                *(uint4*)(dr + 72) = make_uint4(pack2(b4.x, b4.y), pack2(b5.x, b5.y),
                                                pack2(b6.x, b6.y), 0u);
                *(uint4*)(dr + 76) = make_uint4(0u, 0u, 0u, 0u);
            }
        }
        __syncthreads();

        f32x4 acc[4][4] = {};
        #pragma unroll
        for (int kc = 0; kc < KC1; ++kc) {
            const int kHalf = kc * 16 + q * 4;
            bf16x8 a[4], b[4];
            #pragma unroll
            for (int i = 0; i < 4; ++i)
                a[i] = *(const bf16x8*)(&As[(rowBase + 16 * i + ln) * KPU1 + kHalf]);
            #pragma unroll
            for (int j = 0; j < 4; ++j)
                b[j] = *(const bf16x8*)(Wp + (64 * (wv & 1) + 16 * j + ln) * KPU1 + kHalf);
            #pragma unroll
            for (int i = 0; i < 4; ++i)
                #pragma unroll
                for (int j = 0; j < 4; ++j)
                    acc[i][j] = __builtin_amdgcn_mfma_f32_16x16x32_bf16(a[i], b[j], acc[i][j], 0, 0, 0);
        }
        __syncthreads();

        #pragma unroll
        for (int i = 0; i < 4; ++i) {
            #pragma unroll
            for (int r = 0; r < 4; ++r) {
                int wpos = pidx[e0 + rowBase + 16 * i + q * 4 + r];
                u32* orow = hout + (size_t)wpos * 64;
                orow[cbU + ln]      = relu2_pk(acc[i][0][r], acc[i][1][r]);
                orow[cbU + 16 + ln] = relu2_pk(acc[i][2][r], acc[i][3][r]);
            }
        }
    }
}

// ---------------- k_msg: persistent waves, 1-deep software pipeline ----------------
// Each wave owns 32-row subtiles s, s+stride, ... Row p: msg = tmp[sidx[p]] - h[hr],
// hr = USEIDX ? pidx[p] : p; result written back to row hr (same row read).
// Row ownership is a bijection -> prefetch of tile t+1 never races any wave's
// stores of tile t. Raw gathers for t+1 issued right after t's raw regs are
// consumed by the sub+cvt_pk convert, so loads stay in flight across MFMA+store.
template<bool USEIDX>
__global__ __launch_bounds__(256, 2)
void k_msg_t(const int* __restrict__ sidx, const int* __restrict__ pidx,
             const u32* __restrict__ Wp, const u32* __restrict__ tmp,
             u32* __restrict__ h)
{
    const int tid  = threadIdx.x;
    const int lane = tid & 63;
    const int wv   = tid >> 6;
    const int ln   = lane & 15;
    const int q    = lane >> 4;
    const int NT   = NE / 32;            // 25000 subtiles of 32 rows
    const int stride = gridDim.x * 4;
    int s = blockIdx.x * 4 + wv;
    if (s >= NT) return;

    int   srA[2], hrA[2];
    int4  stA[2];                        // store-row quads (USEIDX only)
    uint4 tv[2][4], hv[2][4];            // raw gathered operands

    // ---- prologue: indices + gathers for the first tile
    #pragma unroll
    for (int i = 0; i < 2; ++i) {
        int p = s * 32 + 16 * i + ln;
        srA[i] = sidx[p];
        hrA[i] = USEIDX ? pidx[p] : p;
        if (USEIDX) stA[i] = *(const int4*)(pidx + s * 32 + 16 * i + 4 * q);
    }
    #pragma unroll
    for (int i = 0; i < 2; ++i) {
        const u32* tb = tmp + (size_t)srA[i] * 64 + q * 4;
        const u32* hb = h   + (size_t)hrA[i] * 64 + q * 4;
        #pragma unroll
        for (int kc = 0; kc < 4; ++kc) {
            tv[i][kc] = *(const uint4*)(tb + kc * 16);
            hv[i][kc] = *(const uint4*)(hb + kc * 16);
        }
    }

    while (true) {
        const int sn = s + stride;
        const bool more = sn < NT;       // wave-uniform

        // issue next tile's index loads early (covered by the convert below)
        int  srB[2], hrB[2];
        int4 stB[2];
        if (more) {
            #pragma unroll
            for (int i = 0; i < 2; ++i) {
                int p = sn * 32 + 16 * i + ln;
                srB[i] = sidx[p];
                hrB[i] = USEIDX ? pidx[p] : p;
                if (USEIDX) stB[i] = *(const int4*)(pidx + sn * 32 + 16 * i + 4 * q);
            }
        }

        // convert current raw -> A fragments (frees tv/hv)
        bf16x8 aF[2][4];
        #pragma unroll
        for (int i = 0; i < 2; ++i) {
            #pragma unroll
            for (int kc = 0; kc < 4; ++kc) {
                frag_cast fc;
                fc.u.x = sub2_pk(tv[i][kc].x, hv[i][kc].x);
                fc.u.y = sub2_pk(tv[i][kc].y, hv[i][kc].y);
                fc.u.z = sub2_pk(tv[i][kc].z, hv[i][kc].z);
                fc.u.w = sub2_pk(tv[i][kc].w, hv[i][kc].w);
                aF[i][kc] = fc.v;
            }
        }

        // issue next tile's gathers into the freed raw regs; these stay in
        // flight across the MFMA loop + epilogue and are awaited at the next
        // iteration's convert.
        if (more) {
            #pragma unroll
            for (int i = 0; i < 2; ++i) {
                const u32* tb = tmp + (size_t)srB[i] * 64 + q * 4;
                const u32* hb = h   + (size_t)hrB[i] * 64 + q * 4;
                #pragma unroll
                for (int kc = 0; kc < 4; ++kc) {
                    tv[i][kc] = *(const uint4*)(tb + kc * 16);
                    hv[i][kc] = *(const uint4*)(hb + kc * 16);
                }
            }
        }

        // MFMA: 32 rows x 128 cols, K=128
        f32x4 acc[2][8] = {};
        #pragma unroll
        for (int kc = 0; kc < 4; ++kc) {
            bf16x8 b[8];
            #pragma unroll
            for (int j = 0; j < 8; ++j)
                b[j] = *(const bf16x8*)(Wp + (16 * j + ln) * WHU + kc * 16 + q * 4);
            #pragma unroll
            for (int i = 0; i < 2; ++i)
                #pragma unroll
                for (int j = 0; j < 8; ++j)
                    acc[i][j] = __builtin_amdgcn_mfma_f32_16x16x32_bf16(aF[i][kc], b[j], acc[i][j], 0, 0, 0);
        }

        // epilogue: full 256-B rows, 4 consecutive 64-B segment stores per row
        #pragma unroll
        for (int i = 0; i < 2; ++i) {
            #pragma unroll
            for (int r = 0; r < 4; ++r) {
                int p = s * 32 + 16 * i + 4 * q + r;
                int wrow = USEIDX
                    ? ((r == 0) ? stA[i].x : (r == 1) ? stA[i].y : (r == 2) ? stA[i].z : stA[i].w)
                    : p;
                u32* orow = h + (size_t)wrow * 64;
                #pragma unroll
                for (int a = 0; a < 4; ++a)
                    orow[16 * a + ln] = relu2_pk(acc[i][2 * a][r], acc[i][2 * a + 1][r]);
            }
        }

        if (!more) break;
        s = sn;
        if (USEIDX) { stA[0] = stB[0]; stA[1] = stB[1]; }
    }
}

// ---------------- k_out: 64-node tiles, 4 waves (32x64 each) ----------------
__global__ __launch_bounds__(256, 4)
void k_out(const u32* __restrict__ atomBf, const u32* __restrict__ Wp,
           const u32* __restrict__ tmp, float* __restrict__ out)
{
    __shared__ u32 As[64 * KPU3];   // 37888 B -> 4 blocks/CU
    const int tid = threadIdx.x;
    const int lane = tid & 63;
    const int wv = tid >> 6;
    const int ln = lane & 15;
    const int q  = lane >> 4;
    const int rowBase = 32 * (wv >> 1);
    const int colBase = 64 * (wv & 1);
    const int ntiles = (NN + 63) / 64;

    const int srow = tid >> 2;
    const int qt = tid & 3;
    const uint4 z4 = make_uint4(0u, 0u, 0u, 0u);

    for (int tile = blockIdx.x; tile < ntiles; tile += gridDim.x) {
        const int n0 = tile * 64;
        {
            int n = n0 + srow;
            bool ok = n < NN;
            const u32* ap = atomBf + (size_t)n * ATU;
            const u32* tp = tmp + (size_t)n * 64;
            u32* dr = As + srow * KPU3;
            if (qt == 0) {
                #pragma unroll
                for (int j = 0; j < 9; ++j)
                    *(uint4*)(dr + 4 * j) = ok ? *(const uint4*)(ap + 4 * j) : z4;
            } else if (qt == 1) {
                #pragma unroll
                for (int j = 9; j < 17; ++j)
                    *(uint4*)(dr + 4 * j) = ok ? *(const uint4*)(ap + 4 * j) : z4;
            } else if (qt == 2) {
                #pragma unroll
                for (int j = 0; j < 8; ++j)
                    *(uint4*)(dr + 68 + 4 * j) = ok ? *(const uint4*)(tp + 4 * j) : z4;
                *(uint4*)(dr + 132) = z4;
            } else {
                #pragma unroll
                for (int j = 8; j < 16; ++j)
                    *(uint4*)(dr + 68 + 4 * j) = ok ? *(const uint4*)(tp + 4 * j) : z4;
                *(uint4*)(dr + 136) = z4;
                *(uint4*)(dr + 140) = z4;
            }
        }
        __syncthreads();

        f32x4 acc[2][4] = {};
        #pragma unroll
        for (int kc = 0; kc < KC3; ++kc) {
            const int kHalf = kc * 16 + q * 4;
            bf16x8 a[2], b[4];
            #pragma unroll
            for (int i = 0; i < 2; ++i)
                a[i] = *(const bf16x8*)(&As[(rowBase + 16 * i + ln) * KPU3 + kHalf]);
            #pragma unroll
            for (int j = 0; j < 4; ++j)
                b[j] = *(const bf16x8*)(Wp + (colBase + 16 * j + ln) * KPU3 + kHalf);
            #pragma unroll
            for (int i = 0; i < 2; ++i)
                #pragma unroll
                for (int j = 0; j < 4; ++j)
                    acc[i][j] = __builtin_amdgcn_mfma_f32_16x16x32_bf16(a[i], b[j], acc[i][j], 0, 0, 0);
        }
        __syncthreads();

        #pragma unroll
        for (int i = 0; i < 2; ++i) {
            #pragma unroll
            for (int r = 0; r < 4; ++r) {
                int n = n0 + rowBase + 16 * i + q * 4 + r;
                if (n < NN) {
                    float2* orow = (float2*)(out + (size_t)n * HID);
                    float2 v01, v23;
                    v01.x = relu(acc[i][0][r]); v01.y = relu(acc[i][1][r]);
                    v23.x = relu(acc[i][2][r]); v23.y = relu(acc[i][3][r]);
                    orow[(colBase >> 1) + ln]      = v01;
                    orow[(colBase >> 1) + 16 + ln] = v23;
                }
            }
        }
    }
}

// ---------------- launch ----------------

extern "C" void kernel_launch(void* const* d_in, const int* in_sizes, int n_in,
                              void* d_out, int out_size, void* d_ws, size_t ws_size,
                              hipStream_t stream) {
    const float* atom = (const float*)d_in[0];   // [50000][133]
    const float* bond = (const float*)d_in[1];   // [800000][14]
    const float* Wi   = (const float*)d_in[2];   // [128][147]
    const float* Wh   = (const float*)d_in[3];   // [128][128]
    const float* Wo   = (const float*)d_in[4];   // [128][261]
    const int*   src  = (const int*)d_in[5]; (void)src;
    const int*   dst  = (const int*)d_in[6];
    const int*   rev  = (const int*)d_in[7];
    float* out = (float*)d_out;

    char* ws = (char*)d_ws;
    size_t off = 0;
    auto take = [&](size_t bytes) { char* p = ws + off; off = (off + bytes + 255) & ~(size_t)255; return p; };
    u32* hbuf   = (u32*)take((size_t)NE * 64 * 4);     // 204.8 MB
    u32* tmp    = (u32*)take((size_t)NN * 64 * 4);     // 12.8 MB
    u32* atomBf = (u32*)take((size_t)NN * ATU * 4);    // 13.6 MB
    int* fidx   = (int*)take((size_t)NE * 4);
    int* sidx   = (int*)take((size_t)NE * 4);
    int* posOf  = (int*)take((size_t)NE * 4);
    int* pidx   = (int*)take((size_t)NE * 4);
    int* cnt    = (int*)take((size_t)NN * 4);
    int* lexc   = (int*)take((size_t)NN * 4);
    int* rowptr = (int*)take((size_t)(NN + 1) * 4);
    int* cursor = (int*)take((size_t)NN * 4);
    int* chunkSum = (int*)take(256 * 4);
    int* chunkOff = (int*)take(256 * 4);
    u32* WiP = (u32*)take(128 * KPU1 * 4);
    u32* WhP = (u32*)take(128 * WHU * 4);
    u32* WoP = (u32*)take(128 * KPU3 * 4);
    // total ~245 MB

    cvt_atom<<<2048, 256, 0, stream>>>(atom, atomBf);
    cvt_w<<<48, 256, 0, stream>>>(Wi, WiP, 147, KPU1, 133, 136, 14);
    cvt_w<<<32, 256, 0, stream>>>(Wh, WhP, 128, WHU, 128, 1 << 20, 0);
    cvt_w<<<80, 256, 0, stream>>>(Wo, WoP, 261, KPU3, 133, 136, 128);

    hipMemsetAsync(cnt, 0, (size_t)NN * 4, stream);
    hist<<<1024, 256, 0, stream>>>(dst, cnt);
    scan1<<<NCH, 256, 0, stream>>>(cnt, lexc, chunkSum);
    scan2<<<1, 256, 0, stream>>>(chunkSum, chunkOff);
    scan3<<<NCH, 256, 0, stream>>>(lexc, chunkOff, rowptr, cursor);
    scatter<<<1024, 256, 0, stream>>>(dst, rev, cursor, fidx, sidx, posOf);
    pidx_build<<<1024, 256, 0, stream>>>(fidx, posOf, pidx);

    k_init<<<768, 256, 0, stream>>>(atomBf, bond, fidx, sidx, pidx, WiP, hbuf);   // e-layout
    segsum_t<false><<<2048, 256, 0, stream>>>(rowptr, nullptr, hbuf, tmp);        // sequential
    k_msg_t<false><<<512, 256, 0, stream>>>(sidx, pidx, WhP, tmp, hbuf);          // all-stream -> f-layout
    segsum_t<true><<<2048, 256, 0, stream>>>(rowptr, pidx, hbuf, tmp);            // gather
    k_msg_t<true><<<512, 256, 0, stream>>>(sidx, pidx, WhP, tmp, hbuf);           // random rows -> e-layout
    segsum_t<false><<<2048, 256, 0, stream>>>(rowptr, nullptr, hbuf, tmp);        // sequential
    k_out<<<782, 256, 0, stream>>>(atomBf, WoP, tmp, out);
}

// Round 2
// 672.188 us; speedup vs baseline: 1.2192x; 1.2109x over previous
//
#include <hip/hip_runtime.h>

// DMPNN encoder, MI355X bf16-MFMA, round 8: VMEM-free MFMA loop in k_msg.
//
// Pipeline (pos-space, alternating e-/f-layout; identities:
//   fidx[p]=rev[eidx[p]], sidx[p]=dst[eidx[p]]=src[fidx[p]] (sorted),
//   pidx[p]=posOf[fidx[p]] fix-point-free involution):
//   k_init : staged LDS GEMM, write e-layout @pidx[p]
//   segsum1: sequential (e-layout)
//   k_msg1 : tmp0[sidx[p]] + h0@p -> h1 f-layout @p      (all-stream)
//   segsum2: gather rows pidx[seg]
//   k_msg2 : tmp1[sidx[p]] + h1@pidx[p] -> h2 e-layout @pidx[p]
//   segsum3: sequential
//   k_out  : stream
//
// Round-8 k_msg theory: round-7's prefetch pipeline was flushed every kc
// because B fragments were global loads inside the MFMA loop -- vmcnt is a
// FIFO, so waiting for B forced the next-tile gathers to drain (MfmaUtil
// stuck at 6.4%, SIMDs ~90% idle). Now Wh lives in LDS (staged once per
// persistent block, XOR-swizzled slot^=row&15 to kill the 16-way bank
// conflict of 256-B row stride); B reads are ds_read_b128 on lgkmcnt, so
// the vmem queue holds ONLY prefetch gathers + stores and the single wait
// point per iteration is a gather issued a full iteration earlier. Tile
// shrunk to 16 rows/wave so VGPRs fit 3 waves/SIMD (launch_bounds(256,3),
// grid 768 = 12 waves/CU). asm "+v"(zoff) per iteration defeats LICM so
// the loop-invariant B ds_reads don't get hoisted into 128 registers.
//
// Weight channel permutation c(p) = (p&64) + 2*(p&15) + ((p>>4)&1) + 32*((p>>5)&1)
// == 32*(p>>5) + 2*(p&15) + ((p>>4)&1) for p<128: lane ln's j-pair (2a,2a+1)
// holds adjacent channels 32a+2ln, 32a+2ln+1 -> packed u32 stores.

typedef unsigned int u32;
typedef unsigned short u16;
using bf16x8 = __attribute__((ext_vector_type(8))) __bf16;
using f32x4  = __attribute__((ext_vector_type(4))) float;

#define NN 50000
#define NP 400000
#define NE 800000
#define AF 133
#define HID 128
#define ATU 68      // atomBf row stride in u32
#define KPU1 84     // k_init LDS stride; 80 data u32 = 160 cols = 5 chunks
#define KC1 5
#define WHU 64      // Wh packed row stride (u32) = 256 B rows
#define KPU3 148    // k_out stride; 144 data u32 = 288 cols = 9 chunks
#define KC3 9
#define NCH 196     // scan chunks of 256 covering NN

__device__ __forceinline__ u16 f2bf(float f) {
    union { float f; u32 u; } x; x.f = f;
    u32 r = x.u + 0x7fffu + ((x.u >> 16) & 1u);   // RNE
    return (u16)(r >> 16);
}
__device__ __forceinline__ float bf2f(u16 b) {
    union { u32 u; float f; } x; x.u = ((u32)b) << 16;
    return x.f;
}
__device__ __forceinline__ float lo16(u32 v) { return bf2f((u16)v); }
__device__ __forceinline__ float hi16(u32 v) { return bf2f((u16)(v >> 16)); }
__device__ __forceinline__ u32 pack2(float a, float b) {
    return (u32)f2bf(a) | ((u32)f2bf(b) << 16);
}
__device__ __forceinline__ float relu(float v) { return v > 0.f ? v : 0.f; }

// single-instruction RNE pack of two f32 -> packed bf16x2 (no builtin on gfx950)
__device__ __forceinline__ u32 cvt_pk_bf16(float lo, float hi) {
    u32 r;
    asm("v_cvt_pk_bf16_f32 %0, %1, %2" : "=v"(r) : "v"(lo), "v"(hi));
    return r;
}
__device__ __forceinline__ float bfLO(u32 v) {
    union { u32 u; float f; } x; x.u = v << 16; return x.f;
}
__device__ __forceinline__ float bfHI(u32 v) {
    union { u32 u; float f; } x; x.u = v & 0xffff0000u; return x.f;
}
// (t - h) per packed bf16 pair: exact f32 subtract of bf16 values, RNE pack
__device__ __forceinline__ u32 sub2_pk(u32 t, u32 h) {
    return cvt_pk_bf16(bfLO(t) - bfLO(h), bfHI(t) - bfHI(h));
}
__device__ __forceinline__ u32 relu2_pk(float a, float b) {
    return cvt_pk_bf16(a > 0.f ? a : 0.f, b > 0.f ? b : 0.f);
}

union frag_cast { uint4 u; bf16x8 v; };

// ---------------- precompute kernels ----------------

__global__ void cvt_atom(const float* __restrict__ atom, u32* __restrict__ out) {
    int total = NN * ATU;
    for (int i = blockIdx.x * blockDim.x + threadIdx.x; i < total; i += gridDim.x * blockDim.x) {
        int n = i / ATU;
        int cu = i - n * ATU;
        int k = 2 * cu;
        float f0 = (k < AF) ? atom[n * AF + k] : 0.f;
        float f1 = (k + 1 < AF) ? atom[n * AF + k + 1] : 0.f;
        out[i] = pack2(f0, f1);
    }
}

__device__ __forceinline__ float wcol(const float* W, int n, int Kw, int len1, int off2, int len2, int k) {
    if (k < len1) return W[n * Kw + k];
    int j = k - off2;
    if (j >= 0 && j < len2) return W[n * Kw + len1 + j];
    return 0.f;
}
// Wp row p <- actual channel c(p) (output-channel permutation for packed stores)
__global__ void cvt_w(const float* __restrict__ W, u32* __restrict__ out,
                      int Kw, int KpU, int len1, int off2, int len2) {
    int total = 128 * KpU;
    for (int i = blockIdx.x * blockDim.x + threadIdx.x; i < total; i += gridDim.x * blockDim.x) {
        int p = i / KpU;
        int cu = i - p * KpU;
        int t = p & 63;
        int c = (p & 64) + 2 * (t & 15) + ((t >> 4) & 1) + 32 * ((t >> 5) & 1);
        int k = 2 * cu;
        out[i] = pack2(wcol(W, c, Kw, len1, off2, len2, k),
                       wcol(W, c, Kw, len1, off2, len2, k + 1));
    }
}

// ---------------- CSR build ----------------

__global__ void hist(const int* __restrict__ dst, int* __restrict__ cnt) {
    for (int e = blockIdx.x * blockDim.x + threadIdx.x; e < NE; e += gridDim.x * blockDim.x)
        atomicAdd(&cnt[dst[e]], 1);
}

__global__ void scan1(const int* __restrict__ cnt, int* __restrict__ lexc, int* __restrict__ chunkSum) {
    __shared__ int s[256];
    int t = threadIdx.x, idx = blockIdx.x * 256 + t;
    int v = (idx < NN) ? cnt[idx] : 0;
    s[t] = v; __syncthreads();
    for (int off = 1; off < 256; off <<= 1) {
        int x = (t >= off) ? s[t - off] : 0;
        __syncthreads();
        s[t] += x;
        __syncthreads();
    }
    if (idx < NN) lexc[idx] = s[t] - v;
    if (t == 255) chunkSum[blockIdx.x] = s[255];
}

__global__ void scan2(const int* __restrict__ chunkSum, int* __restrict__ chunkOff) {
    __shared__ int s[256];
    int t = threadIdx.x;
    int v = (t < NCH) ? chunkSum[t] : 0;
    s[t] = v; __syncthreads();
    for (int off = 1; off < 256; off <<= 1) {
        int x = (t >= off) ? s[t - off] : 0;
        __syncthreads();
        s[t] += x;
        __syncthreads();
    }
    if (t < NCH) chunkOff[t] = s[t] - v;
}

__global__ void scan3(const int* __restrict__ lexc, const int* __restrict__ chunkOff,
                      int* __restrict__ rowptr, int* __restrict__ cursor) {
    int idx = blockIdx.x * 256 + threadIdx.x;
    if (idx < NN) {
        int v = lexc[idx] + chunkOff[blockIdx.x];
        rowptr[idx] = v;
        cursor[idx] = v;
    }
    if (idx == 0) rowptr[NN] = NE;
}

__global__ void scatter(const int* __restrict__ dst, const int* __restrict__ rev,
                        int* __restrict__ cursor, int* __restrict__ fidx,
                        int* __restrict__ sidx, int* __restrict__ posOf) {
    for (int e = blockIdx.x * blockDim.x + threadIdx.x; e < NE; e += gridDim.x * blockDim.x) {
        int d = dst[e];
        int pos = atomicAdd(&cursor[d], 1);
        fidx[pos] = rev[e];
        sidx[pos] = d;        // = src[fidx[pos]], nondecreasing over pos
        posOf[e] = pos;
    }
}

__global__ void pidx_build(const int* __restrict__ fidx, const int* __restrict__ posOf,
                           int* __restrict__ pidx) {
    for (int p = blockIdx.x * blockDim.x + threadIdx.x; p < NE; p += gridDim.x * blockDim.x)
        pidx[p] = posOf[fidx[p]];
}

// ---------------- segment sum ----------------
// one wave per node; chunk = 4 rows, lane l -> row (l>>4), uint4 col group (l&15).
template<bool G>
__global__ __launch_bounds__(256)
void segsum_t(const int* __restrict__ rowptr, const int* __restrict__ gat,
              const u32* __restrict__ h, u32* __restrict__ tmp) {
    const int lane = threadIdx.x & 63;
    const int wv = threadIdx.x >> 6;
    const int rsel = lane >> 4;
    const int cg = lane & 15;
    const int nwaves = gridDim.x * 4;
    for (int n = blockIdx.x * 4 + wv; n < NN; n += nwaves) {
        int beg = rowptr[n], end = rowptr[n + 1];
        float a0 = 0, a1 = 0, a2 = 0, a3 = 0, a4 = 0, a5 = 0, a6 = 0, a7 = 0;
        int i = beg;
        for (; i + 8 <= end; i += 8) {
            int rA = G ? gat[i + rsel] : (i + rsel);
            int rB = G ? gat[i + 4 + rsel] : (i + 4 + rsel);
            uint4 hA = *(const uint4*)(h + (size_t)rA * 64 + 4 * cg);
            uint4 hB = *(const uint4*)(h + (size_t)rB * 64 + 4 * cg);
            a0 += lo16(hA.x) + lo16(hB.x); a1 += hi16(hA.x) + hi16(hB.x);
            a2 += lo16(hA.y) + lo16(hB.y); a3 += hi16(hA.y) + hi16(hB.y);
            a4 += lo16(hA.z) + lo16(hB.z); a5 += hi16(hA.z) + hi16(hB.z);
            a6 += lo16(hA.w) + lo16(hB.w); a7 += hi16(hA.w) + hi16(hB.w);
        }
        for (; i < end; i += 4) {
            if (i + rsel < end) {
                int rA = G ? gat[i + rsel] : (i + rsel);
                uint4 hA = *(const uint4*)(h + (size_t)rA * 64 + 4 * cg);
                a0 += lo16(hA.x); a1 += hi16(hA.x);
                a2 += lo16(hA.y); a3 += hi16(hA.y);
                a4 += lo16(hA.z); a5 += hi16(hA.z);
                a6 += lo16(hA.w); a7 += hi16(hA.w);
            }
        }
        a0 += __shfl_xor(a0, 16); a0 += __shfl_xor(a0, 32);
        a1 += __shfl_xor(a1, 16); a1 += __shfl_xor(a1, 32);
        a2 += __shfl_xor(a2, 16); a2 += __shfl_xor(a2, 32);
        a3 += __shfl_xor(a3, 16); a3 += __shfl_xor(a3, 32);
        a4 += __shfl_xor(a4, 16); a4 += __shfl_xor(a4, 32);
        a5 += __shfl_xor(a5, 16); a5 += __shfl_xor(a5, 32);
        a6 += __shfl_xor(a6, 16); a6 += __shfl_xor(a6, 32);
        a7 += __shfl_xor(a7, 16); a7 += __shfl_xor(a7, 32);
        if (rsel == 0) {
            uint4 o;
            o.x = pack2(a0, a1); o.y = pack2(a2, a3);
            o.z = pack2(a4, a5); o.w = pack2(a6, a7);
            *(uint4*)(tmp + (size_t)n * 64 + 4 * cg) = o;
        }
    }
}

// ---------------- k_init: pos-sequential 128-row tiles, LDS-staged ----------------
// writes e-layout: h0(fidx[p]) -> row pidx[p]
__global__ __launch_bounds__(256, 3)
void k_init(const u32* __restrict__ atomBf, const float* __restrict__ bond,
            const int* __restrict__ fidx, const int* __restrict__ sidx,
            const int* __restrict__ pidx, const u32* __restrict__ Wp,
            u32* __restrict__ hout)
{
    __shared__ u32 As[128 * KPU1];   // 43008 B -> 3 blocks/CU
    const int tid = threadIdx.x;
    const int lane = tid & 63;
    const int wv = tid >> 6;
    const int ln = lane & 15;
    const int q  = lane >> 4;
    const int rowBase = 64 * (wv >> 1);
    const int cbU = 32 * (wv & 1);
    const int ntiles = NE / 128;

    const int srow = tid >> 1;
    const int half = tid & 1;

    for (int tile = blockIdx.x; tile < ntiles; tile += gridDim.x) {
        const int e0 = tile * 128;
        {
            int p = e0 + srow;
            const u32* ap = atomBf + (size_t)sidx[p] * ATU;
            u32* dr = As + srow * KPU1;
            if (half == 0) {
                #pragma unroll
                for (int j = 0; j < 10; ++j)
                    *(uint4*)(dr + 4 * j) = *(const uint4*)(ap + 4 * j);
            } else {
                #pragma unroll
                for (int j = 10; j < 17; ++j)
                    *(uint4*)(dr + 4 * j) = *(const uint4*)(ap + 4 * j);
                const float* bp = bond + (size_t)fidx[p] * 14;
                float2 b0 = *(const float2*)(bp + 0);
                float2 b1 = *(const float2*)(bp + 2);
                float2 b2 = *(const float2*)(bp + 4);
                float2 b3 = *(const float2*)(bp + 6);
                float2 b4 = *(const float2*)(bp + 8);
                float2 b5 = *(const float2*)(bp + 10);
                float2 b6 = *(const float2*)(bp + 12);
                *(uint4*)(dr + 68) = make_uint4(pack2(b0.x, b0.y), pack2(b1.x, b1.y),
                                                pack2(b2.x, b2.y), pack2(b3.x, b3.y));
                *(uint4*)(dr + 72) = make_uint4(pack2(b4.x, b4.y), pack2(b5.x, b5.y),
                                                pack2(b6.x, b6.y), 0u);
                *(uint4*)(dr + 76) = make_uint4(0u, 0u, 0u, 0u);
            }
        }
        __syncthreads();

        f32x4 acc[4][4] = {};
        #pragma unroll
        for (int kc = 0; kc < KC1; ++kc) {
            const int kHalf = kc * 16 + q * 4;
            bf16x8 a[4], b[4];
            #pragma unroll
            for (int i = 0; i < 4; ++i)
                a[i] = *(const bf16x8*)(&As[(rowBase + 16 * i + ln) * KPU1 + kHalf]);
            #pragma unroll
            for (int j = 0; j < 4; ++j)
                b[j] = *(const bf16x8*)(Wp + (64 * (wv & 1) + 16 * j + ln) * KPU1 + kHalf);
            #pragma unroll
            for (int i = 0; i < 4; ++i)
                #pragma unroll
                for (int j = 0; j < 4; ++j)
                    acc[i][j] = __builtin_amdgcn_mfma_f32_16x16x32_bf16(a[i], b[j], acc[i][j], 0, 0, 0);
        }
        __syncthreads();

        #pragma unroll
        for (int i = 0; i < 4; ++i) {
            #pragma unroll
            for (int r = 0; r < 4; ++r) {
                int wpos = pidx[e0 + rowBase + 16 * i + q * 4 + r];
                u32* orow = hout + (size_t)wpos * 64;
                orow[cbU + ln]      = relu2_pk(acc[i][0][r], acc[i][1][r]);
                orow[cbU + 16 + ln] = relu2_pk(acc[i][2][r], acc[i][3][r]);
            }
        }
    }
}

// ---------------- k_msg: persistent waves, VMEM-free MFMA loop ----------------
// Wh staged once into LDS (XOR-swizzled), B via ds_read_b128 (lgkmcnt), so the
// vmem FIFO holds only prefetch gathers + stores: one wait point/iteration on
// gathers issued a full iteration earlier. 16-row tiles, 12 waves/CU.
// Row p: msg = tmp[sidx[p]] - h[hr], hr = USEIDX ? pidx[p] : p; written back
// to row hr. Row ownership is a bijection -> prefetch never races stores.
template<bool USEIDX>
__global__ __launch_bounds__(256, 3)
void k_msg_t(const int* __restrict__ sidx, const int* __restrict__ pidx,
             const u32* __restrict__ Wp, const u32* __restrict__ tmp,
             u32* __restrict__ h)
{
    __shared__ u32 Wlds[128 * 64];   // 32 KB; slot phys = slot ^ (row&15)
    const int tid  = threadIdx.x;
    const int lane = tid & 63;
    const int wv   = tid >> 6;
    const int ln   = lane & 15;
    const int q    = lane >> 4;

    // one-time Wh stage with XOR swizzle (kills 16-way conflict of 256-B rows)
    {
        const int row = tid >> 1;        // 128 rows, 2 threads/row
        const int half = tid & 1;        // 8 slots of 16 B each
        const int rx = row & 15;
        #pragma unroll
        for (int sl = 0; sl < 8; ++sl) {
            int L = half * 8 + sl;
            int P = L ^ rx;
            *(uint4*)(Wlds + row * 64 + P * 4) = *(const uint4*)(Wp + row * 64 + L * 4);
        }
    }
    __syncthreads();

    const int NT = NE / 16;              // 50000 tiles of 16 rows
    const int stride = gridDim.x * 4;
    int s = blockIdx.x * 4 + wv;
    if (s >= NT) return;

    int4  stA;                           // store-row quad (USEIDX only)
    uint4 tv[4], hv[4];                  // raw gathered operands

    // ---- prologue: gathers for the first tile
    {
        int p = s * 16 + ln;
        int sr = sidx[p];
        int hr = USEIDX ? pidx[p] : p;
        if (USEIDX) stA = *(const int4*)(pidx + s * 16 + 4 * q);
        const u32* tb = tmp + (size_t)sr * 64 + q * 4;
        const u32* hb = h   + (size_t)hr * 64 + q * 4;
        #pragma unroll
        for (int kc = 0; kc < 4; ++kc) {
            tv[kc] = *(const uint4*)(tb + kc * 16);
            hv[kc] = *(const uint4*)(hb + kc * 16);
        }
    }

    while (true) {
        const int sn = s + stride;
        const bool more = sn < NT;       // wave-uniform

        // next tile's index loads (covered by the convert below)
        int srB = 0, hrB = 0;
        int4 stB;
        if (more) {
            int p = sn * 16 + ln;
            srB = sidx[p];
            hrB = USEIDX ? pidx[p] : p;
            if (USEIDX) stB = *(const int4*)(pidx + sn * 16 + 4 * q);
        }

        // convert current raw -> A fragments (frees tv/hv)
        bf16x8 aF[4];
        #pragma unroll
        for (int kc = 0; kc < 4; ++kc) {
            frag_cast fc;
            fc.u.x = sub2_pk(tv[kc].x, hv[kc].x);
            fc.u.y = sub2_pk(tv[kc].y, hv[kc].y);
            fc.u.z = sub2_pk(tv[kc].z, hv[kc].z);
            fc.u.w = sub2_pk(tv[kc].w, hv[kc].w);
            aF[kc] = fc.v;
        }

        // prefetch next tile's gathers into the freed regs; they stay in
        // flight across the MFMA loop + stores (no VMEM waits below).
        if (more) {
            const u32* tb = tmp + (size_t)srB * 64 + q * 4;
            const u32* hb = h   + (size_t)hrB * 64 + q * 4;
            #pragma unroll
            for (int kc = 0; kc < 4; ++kc) {
                tv[kc] = *(const uint4*)(tb + kc * 16);
                hv[kc] = *(const uint4*)(hb + kc * 16);
            }
        }

        // MFMA 16x128, K=128; B from LDS only (lgkmcnt -> vmem FIFO untouched).
        u32 zoff = 0;
        asm volatile("" : "+v"(zoff));   // defeat LICM: keep B ds_reads in-loop
        f32x4 acc[8] = {};
        #pragma unroll
        for (int kc = 0; kc < 4; ++kc) {
            const u32* wrow = Wlds + zoff + ln * 64 + (((kc * 4 + q) ^ ln) << 2);
            #pragma unroll
            for (int j = 0; j < 8; ++j) {
                bf16x8 b = *(const bf16x8*)(wrow + j * 1024);
                acc[j] = __builtin_amdgcn_mfma_f32_16x16x32_bf16(aF[kc], b, acc[j], 0, 0, 0);
            }
        }

        // epilogue: full 256-B rows, 4 consecutive 64-B segment stores per row
        #pragma unroll
        for (int r = 0; r < 4; ++r) {
            int wrow = USEIDX
                ? ((r == 0) ? stA.x : (r == 1) ? stA.y : (r == 2) ? stA.z : stA.w)
                : (s * 16 + 4 * q + r);
            u32* orow = h + (size_t)wrow * 64;
            #pragma unroll
            for (int a = 0; a < 4; ++a)
                orow[16 * a + ln] = relu2_pk(acc[2 * a][r], acc[2 * a + 1][r]);
        }

        if (!more) break;
        s = sn;
        if (USEIDX) stA = stB;
    }
}

// ---------------- k_out: 64-node tiles, 4 waves (32x64 each) ----------------
__global__ __launch_bounds__(256, 4)
void k_out(const u32* __restrict__ atomBf, const u32* __restrict__ Wp,
           const u32* __restrict__ tmp, float* __restrict__ out)
{
    __shared__ u32 As[64 * KPU3];   // 37888 B -> 4 blocks/CU
    const int tid = threadIdx.x;
    const int lane = tid & 63;
    const int wv = tid >> 6;
    const int ln = lane & 15;
    const int q  = lane >> 4;
    const int rowBase = 32 * (wv >> 1);
    const int colBase = 64 * (wv & 1);
    const int ntiles = (NN + 63) / 64;

    const int srow = tid >> 2;
    const int qt = tid & 3;
    const uint4 z4 = make_uint4(0u, 0u, 0u, 0u);

    for (int tile = blockIdx.x; tile < ntiles; tile += gridDim.x) {
        const int n0 = tile * 64;
        {
            int n = n0 + srow;
            bool ok = n < NN;
            const u32* ap = atomBf + (size_t)n * ATU;
            const u32* tp = tmp + (size_t)n * 64;
            u32* dr = As + srow * KPU3;
            if (qt == 0) {
                #pragma unroll
                for (int j = 0; j < 9; ++j)
                    *(uint4*)(dr + 4 * j) = ok ? *(const uint4*)(ap + 4 * j) : z4;
            } else if (qt == 1) {
                #pragma unroll
                for (int j = 9; j < 17; ++j)
                    *(uint4*)(dr + 4 * j) = ok ? *(const uint4*)(ap + 4 * j) : z4;
            } else if (qt == 2) {
                #pragma unroll
                for (int j = 0; j < 8; ++j)
                    *(uint4*)(dr + 68 + 4 * j) = ok ? *(const uint4*)(tp + 4 * j) : z4;
                *(uint4*)(dr + 132) = z4;
            } else {
                #pragma unroll
                for (int j = 8; j < 16; ++j)
                    *(uint4*)(dr + 68 + 4 * j) = ok ? *(const uint4*)(tp + 4 * j) : z4;
                *(uint4*)(dr + 136) = z4;
                *(uint4*)(dr + 140) = z4;
            }
        }
        __syncthreads();

        f32x4 acc[2][4] = {};
        #pragma unroll
        for (int kc = 0; kc < KC3; ++kc) {
            const int kHalf = kc * 16 + q * 4;
            bf16x8 a[2], b[4];
            #pragma unroll
            for (int i = 0; i < 2; ++i)
                a[i] = *(const bf16x8*)(&As[(rowBase + 16 * i + ln) * KPU3 + kHalf]);
            #pragma unroll
            for (int j = 0; j < 4; ++j)
                b[j] = *(const bf16x8*)(Wp + (colBase + 16 * j + ln) * KPU3 + kHalf);
            #pragma unroll
            for (int i = 0; i < 2; ++i)
                #pragma unroll
                for (int j = 0; j < 4; ++j)
                    acc[i][j] = __builtin_amdgcn_mfma_f32_16x16x32_bf16(a[i], b[j], acc[i][j], 0, 0, 0);
        }
        __syncthreads();

        #pragma unroll
        for (int i = 0; i < 2; ++i) {
            #pragma unroll
            for (int r = 0; r < 4; ++r) {
                int n = n0 + rowBase + 16 * i + q * 4 + r;
                if (n < NN) {
                    float2* orow = (float2*)(out + (size_t)n * HID);
                    float2 v01, v23;
                    v01.x = relu(acc[i][0][r]); v01.y = relu(acc[i][1][r]);
                    v23.x = relu(acc[i][2][r]); v23.y = relu(acc[i][3][r]);
                    orow[(colBase >> 1) + ln]      = v01;
                    orow[(colBase >> 1) + 16 + ln] = v23;
                }
            }
        }
    }
}

// ---------------- launch ----------------

extern "C" void kernel_launch(void* const* d_in, const int* in_sizes, int n_in,
                              void* d_out, int out_size, void* d_ws, size_t ws_size,
                              hipStream_t stream) {
    const float* atom = (const float*)d_in[0];   // [50000][133]
    const float* bond = (const float*)d_in[1];   // [800000][14]
    const float* Wi   = (const float*)d_in[2];   // [128][147]
    const float* Wh   = (const float*)d_in[3];   // [128][128]
    const float* Wo   = (const float*)d_in[4];   // [128][261]
    const int*   src  = (const int*)d_in[5]; (void)src;
    const int*   dst  = (const int*)d_in[6];
    const int*   rev  = (const int*)d_in[7];
    float* out = (float*)d_out;

    char* ws = (char*)d_ws;
    size_t off = 0;
    auto take = [&](size_t bytes) { char* p = ws + off; off = (off + bytes + 255) & ~(size_t)255; return p; };
    u32* hbuf   = (u32*)take((size_t)NE * 64 * 4);     // 204.8 MB
    u32* tmp    = (u32*)take((size_t)NN * 64 * 4);     // 12.8 MB
    u32* atomBf = (u32*)take((size_t)NN * ATU * 4);    // 13.6 MB
    int* fidx   = (int*)take((size_t)NE * 4);
    int* sidx   = (int*)take((size_t)NE * 4);
    int* posOf  = (int*)take((size_t)NE * 4);
    int* pidx   = (int*)take((size_t)NE * 4);
    int* cnt    = (int*)take((size_t)NN * 4);
    int* lexc   = (int*)take((size_t)NN * 4);
    int* rowptr = (int*)take((size_t)(NN + 1) * 4);
    int* cursor = (int*)take((size_t)NN * 4);
    int* chunkSum = (int*)take(256 * 4);
    int* chunkOff = (int*)take(256 * 4);
    u32* WiP = (u32*)take(128 * KPU1 * 4);
    u32* WhP = (u32*)take(128 * WHU * 4);
    u32* WoP = (u32*)take(128 * KPU3 * 4);
    // total ~245 MB

    cvt_atom<<<2048, 256, 0, stream>>>(atom, atomBf);
    cvt_w<<<48, 256, 0, stream>>>(Wi, WiP, 147, KPU1, 133, 136, 14);
    cvt_w<<<32, 256, 0, stream>>>(Wh, WhP, 128, WHU, 128, 1 << 20, 0);
    cvt_w<<<80, 256, 0, stream>>>(Wo, WoP, 261, KPU3, 133, 136, 128);

    hipMemsetAsync(cnt, 0, (size_t)NN * 4, stream);
    hist<<<1024, 256, 0, stream>>>(dst, cnt);
    scan1<<<NCH, 256, 0, stream>>>(cnt, lexc, chunkSum);
    scan2<<<1, 256, 0, stream>>>(chunkSum, chunkOff);
    scan3<<<NCH, 256, 0, stream>>>(lexc, chunkOff, rowptr, cursor);
    scatter<<<1024, 256, 0, stream>>>(dst, rev, cursor, fidx, sidx, posOf);
    pidx_build<<<1024, 256, 0, stream>>>(fidx, posOf, pidx);

    k_init<<<768, 256, 0, stream>>>(atomBf, bond, fidx, sidx, pidx, WiP, hbuf);   // e-layout
    segsum_t<false><<<2048, 256, 0, stream>>>(rowptr, nullptr, hbuf, tmp);        // sequential
    k_msg_t<false><<<768, 256, 0, stream>>>(sidx, pidx, WhP, tmp, hbuf);          // all-stream -> f-layout
    segsum_t<true><<<2048, 256, 0, stream>>>(rowptr, pidx, hbuf, tmp);            // gather
    k_msg_t<true><<<768, 256, 0, stream>>>(sidx, pidx, WhP, tmp, hbuf);           // random rows -> e-layout
    segsum_t<false><<<2048, 256, 0, stream>>>(rowptr, nullptr, hbuf, tmp);        // sequential
    k_out<<<782, 256, 0, stream>>>(atomBf, WoP, tmp, out);
}

// Round 3
// 595.503 us; speedup vs baseline: 1.3762x; 1.1288x over previous
//
#include <hip/hip_runtime.h>

// DMPNN encoder, MI355X bf16-MFMA, round 9: k_init ported to the k_msg
// structure (LDS-free A build, VMEM-free MFMA loop, full-row stores).
//
// Pipeline (pos-space, alternating e-/f-layout; identities:
//   fidx[p]=rev[eidx[p]], sidx[p]=dst[eidx[p]]=src[fidx[p]] (sorted),
//   pidx[p]=posOf[fidx[p]] fix-point-free involution):
//   k_init : persistent waves, Wi in LDS, write e-layout @pidx[p]
//   segsum1: sequential (e-layout)
//   k_msg1 : tmp0[sidx[p]] + h0@p -> h1 f-layout @p      (all-stream)
//   segsum2: gather rows pidx[seg]
//   k_msg2 : tmp1[sidx[p]] + h1@pidx[p] -> h2 e-layout @pidx[p]
//   segsum3: sequential
//   k_out  : stream
//
// Round-9 k_init theory: rocprof showed FETCH 228 MB (ideal ~130) +
// WRITE 236 (ideal ~205) -> partial-line RMW from 256-B hout rows written
// as 4x64-B chunks split across TWO waves (column halves) at random pidx;
// plus MfmaUtil 8% / VALU 9% / HBM 38% -> latency-bound barrier-paced
// stage->MFMA(global B)->scatter structure, the exact disease k_msg had in
// round 7. Port the round-8 cure: 16x128 wave tiles; A fragments built
// straight from global (kc0-3 are raw atomBf uint4s -- atomBf is already
// bf16-packed; kc4 tail assembles atom u32 64..67 / bond cvt_pk / zeros
// per q-group); Wi staged once into LDS XOR-swizzled (phys=slot^(row&7),
// 24-slot stride) so the MFMA loop is VMEM-free; 1-deep prefetch pipeline;
// epilogue writes FULL 256-B rows from one wave (no RMW).
//
// Weight channel permutation c(p) = (p&64) + 2*(p&15) + ((p>>4)&1) + 32*((p>>5)&1)
// == 32*(p>>5) + 2*(p&15) + ((p>>4)&1) for p<128: lane ln's j-pair (2a,2a+1)
// holds adjacent channels 32a+2ln, 32a+2ln+1 -> packed u32 stores.

typedef unsigned int u32;
typedef unsigned short u16;
using bf16x8 = __attribute__((ext_vector_type(8))) __bf16;
using f32x4  = __attribute__((ext_vector_type(4))) float;

#define NN 50000
#define NP 400000
#define NE 800000
#define AF 133
#define HID 128
#define ATU 68      // atomBf row stride in u32
#define KPU1 80     // Wi packed row stride in u32 (160 cols = 5 kc chunks)
#define WHU 64      // Wh packed row stride (u32) = 256 B rows
#define KPU3 148    // k_out stride; 144 data u32 = 288 cols = 9 chunks
#define KC3 9
#define NCH 196     // scan chunks of 256 covering NN

__device__ __forceinline__ u16 f2bf(float f) {
    union { float f; u32 u; } x; x.f = f;
    u32 r = x.u + 0x7fffu + ((x.u >> 16) & 1u);   // RNE
    return (u16)(r >> 16);
}
__device__ __forceinline__ float bf2f(u16 b) {
    union { u32 u; float f; } x; x.u = ((u32)b) << 16;
    return x.f;
}
__device__ __forceinline__ float lo16(u32 v) { return bf2f((u16)v); }
__device__ __forceinline__ float hi16(u32 v) { return bf2f((u16)(v >> 16)); }
__device__ __forceinline__ u32 pack2(float a, float b) {
    return (u32)f2bf(a) | ((u32)f2bf(b) << 16);
}
__device__ __forceinline__ float relu(float v) { return v > 0.f ? v : 0.f; }

// single-instruction RNE pack of two f32 -> packed bf16x2 (no builtin on gfx950)
__device__ __forceinline__ u32 cvt_pk_bf16(float lo, float hi) {
    u32 r;
    asm("v_cvt_pk_bf16_f32 %0, %1, %2" : "=v"(r) : "v"(lo), "v"(hi));
    return r;
}
__device__ __forceinline__ float bfLO(u32 v) {
    union { u32 u; float f; } x; x.u = v << 16; return x.f;
}
__device__ __forceinline__ float bfHI(u32 v) {
    union { u32 u; float f; } x; x.u = v & 0xffff0000u; return x.f;
}
// (t - h) per packed bf16 pair: exact f32 subtract of bf16 values, RNE pack
__device__ __forceinline__ u32 sub2_pk(u32 t, u32 h) {
    return cvt_pk_bf16(bfLO(t) - bfLO(h), bfHI(t) - bfHI(h));
}
__device__ __forceinline__ u32 relu2_pk(float a, float b) {
    return cvt_pk_bf16(a > 0.f ? a : 0.f, b > 0.f ? b : 0.f);
}

union frag_cast { uint4 u; bf16x8 v; };

// ---------------- precompute kernels ----------------

__global__ void cvt_atom(const float* __restrict__ atom, u32* __restrict__ out) {
    int total = NN * ATU;
    for (int i = blockIdx.x * blockDim.x + threadIdx.x; i < total; i += gridDim.x * blockDim.x) {
        int n = i / ATU;
        int cu = i - n * ATU;
        int k = 2 * cu;
        float f0 = (k < AF) ? atom[n * AF + k] : 0.f;
        float f1 = (k + 1 < AF) ? atom[n * AF + k + 1] : 0.f;
        out[i] = pack2(f0, f1);
    }
}

__device__ __forceinline__ float wcol(const float* W, int n, int Kw, int len1, int off2, int len2, int k) {
    if (k < len1) return W[n * Kw + k];
    int j = k - off2;
    if (j >= 0 && j < len2) return W[n * Kw + len1 + j];
    return 0.f;
}
// Wp row p <- actual channel c(p) (output-channel permutation for packed stores)
__global__ void cvt_w(const float* __restrict__ W, u32* __restrict__ out,
                      int Kw, int KpU, int len1, int off2, int len2) {
    int total = 128 * KpU;
    for (int i = blockIdx.x * blockDim.x + threadIdx.x; i < total; i += gridDim.x * blockDim.x) {
        int p = i / KpU;
        int cu = i - p * KpU;
        int t = p & 63;
        int c = (p & 64) + 2 * (t & 15) + ((t >> 4) & 1) + 32 * ((t >> 5) & 1);
        int k = 2 * cu;
        out[i] = pack2(wcol(W, c, Kw, len1, off2, len2, k),
                       wcol(W, c, Kw, len1, off2, len2, k + 1));
    }
}

// ---------------- CSR build ----------------

__global__ void hist(const int* __restrict__ dst, int* __restrict__ cnt) {
    for (int e = blockIdx.x * blockDim.x + threadIdx.x; e < NE; e += gridDim.x * blockDim.x)
        atomicAdd(&cnt[dst[e]], 1);
}

__global__ void scan1(const int* __restrict__ cnt, int* __restrict__ lexc, int* __restrict__ chunkSum) {
    __shared__ int s[256];
    int t = threadIdx.x, idx = blockIdx.x * 256 + t;
    int v = (idx < NN) ? cnt[idx] : 0;
    s[t] = v; __syncthreads();
    for (int off = 1; off < 256; off <<= 1) {
        int x = (t >= off) ? s[t - off] : 0;
        __syncthreads();
        s[t] += x;
        __syncthreads();
    }
    if (idx < NN) lexc[idx] = s[t] - v;
    if (t == 255) chunkSum[blockIdx.x] = s[255];
}

__global__ void scan2(const int* __restrict__ chunkSum, int* __restrict__ chunkOff) {
    __shared__ int s[256];
    int t = threadIdx.x;
    int v = (t < NCH) ? chunkSum[t] : 0;
    s[t] = v; __syncthreads();
    for (int off = 1; off < 256; off <<= 1) {
        int x = (t >= off) ? s[t - off] : 0;
        __syncthreads();
        s[t] += x;
        __syncthreads();
    }
    if (t < NCH) chunkOff[t] = s[t] - v;
}

__global__ void scan3(const int* __restrict__ lexc, const int* __restrict__ chunkOff,
                      int* __restrict__ rowptr, int* __restrict__ cursor) {
    int idx = blockIdx.x * 256 + threadIdx.x;
    if (idx < NN) {
        int v = lexc[idx] + chunkOff[blockIdx.x];
        rowptr[idx] = v;
        cursor[idx] = v;
    }
    if (idx == 0) rowptr[NN] = NE;
}

__global__ void scatter(const int* __restrict__ dst, const int* __restrict__ rev,
                        int* __restrict__ cursor, int* __restrict__ fidx,
                        int* __restrict__ sidx, int* __restrict__ posOf) {
    for (int e = blockIdx.x * blockDim.x + threadIdx.x; e < NE; e += gridDim.x * blockDim.x) {
        int d = dst[e];
        int pos = atomicAdd(&cursor[d], 1);
        fidx[pos] = rev[e];
        sidx[pos] = d;        // = src[fidx[pos]], nondecreasing over pos
        posOf[e] = pos;
    }
}

__global__ void pidx_build(const int* __restrict__ fidx, const int* __restrict__ posOf,
                           int* __restrict__ pidx) {
    for (int p = blockIdx.x * blockDim.x + threadIdx.x; p < NE; p += gridDim.x * blockDim.x)
        pidx[p] = posOf[fidx[p]];
}

// ---------------- segment sum ----------------
// one wave per node; chunk = 4 rows, lane l -> row (l>>4), uint4 col group (l&15).
template<bool G>
__global__ __launch_bounds__(256)
void segsum_t(const int* __restrict__ rowptr, const int* __restrict__ gat,
              const u32* __restrict__ h, u32* __restrict__ tmp) {
    const int lane = threadIdx.x & 63;
    const int wv = threadIdx.x >> 6;
    const int rsel = lane >> 4;
    const int cg = lane & 15;
    const int nwaves = gridDim.x * 4;
    for (int n = blockIdx.x * 4 + wv; n < NN; n += nwaves) {
        int beg = rowptr[n], end = rowptr[n + 1];
        float a0 = 0, a1 = 0, a2 = 0, a3 = 0, a4 = 0, a5 = 0, a6 = 0, a7 = 0;
        int i = beg;
        for (; i + 8 <= end; i += 8) {
            int rA = G ? gat[i + rsel] : (i + rsel);
            int rB = G ? gat[i + 4 + rsel] : (i + 4 + rsel);
            uint4 hA = *(const uint4*)(h + (size_t)rA * 64 + 4 * cg);
            uint4 hB = *(const uint4*)(h + (size_t)rB * 64 + 4 * cg);
            a0 += lo16(hA.x) + lo16(hB.x); a1 += hi16(hA.x) + hi16(hB.x);
            a2 += lo16(hA.y) + lo16(hB.y); a3 += hi16(hA.y) + hi16(hB.y);
            a4 += lo16(hA.z) + lo16(hB.z); a5 += hi16(hA.z) + hi16(hB.z);
            a6 += lo16(hA.w) + lo16(hB.w); a7 += hi16(hA.w) + hi16(hB.w);
        }
        for (; i < end; i += 4) {
            if (i + rsel < end) {
                int rA = G ? gat[i + rsel] : (i + rsel);
                uint4 hA = *(const uint4*)(h + (size_t)rA * 64 + 4 * cg);
                a0 += lo16(hA.x); a1 += hi16(hA.x);
                a2 += lo16(hA.y); a3 += hi16(hA.y);
                a4 += lo16(hA.z); a5 += hi16(hA.z);
                a6 += lo16(hA.w); a7 += hi16(hA.w);
            }
        }
        a0 += __shfl_xor(a0, 16); a0 += __shfl_xor(a0, 32);
        a1 += __shfl_xor(a1, 16); a1 += __shfl_xor(a1, 32);
        a2 += __shfl_xor(a2, 16); a2 += __shfl_xor(a2, 32);
        a3 += __shfl_xor(a3, 16); a3 += __shfl_xor(a3, 32);
        a4 += __shfl_xor(a4, 16); a4 += __shfl_xor(a4, 32);
        a5 += __shfl_xor(a5, 16); a5 += __shfl_xor(a5, 32);
        a6 += __shfl_xor(a6, 16); a6 += __shfl_xor(a6, 32);
        a7 += __shfl_xor(a7, 16); a7 += __shfl_xor(a7, 32);
        if (rsel == 0) {
            uint4 o;
            o.x = pack2(a0, a1); o.y = pack2(a2, a3);
            o.z = pack2(a4, a5); o.w = pack2(a6, a7);
            *(uint4*)(tmp + (size_t)n * 64 + 4 * cg) = o;
        }
    }
}

// ---------------- k_init: persistent waves, VMEM-free MFMA loop ----------------
// A row p = concat(atomBf[sidx[p]] (136 cols), bondBf[fidx[p]] (14 cols), pad)
// built straight from global per lane: kc0-3 slices are raw atomBf uint4s;
// kc4 tail: q0 = atom u32 64..67, q1 = bond f0..7 cvt, q2 = bond f8..13 cvt
// + pad, q3 = zeros (Wi cols 150..159 are zero so pad values are harmless,
// but we zero them anyway). Wi in LDS (XOR-swizzled), 1-deep prefetch
// pipeline, full 256-B row stores to hout[pidx[p]] (e-layout).
__global__ __launch_bounds__(256, 3)
void k_init(const u32* __restrict__ atomBf, const float* __restrict__ bond,
            const int* __restrict__ fidx, const int* __restrict__ sidx,
            const int* __restrict__ pidx, const u32* __restrict__ Wp,
            u32* __restrict__ hout)
{
    __shared__ u32 Wlds[128 * 96];   // 49152 B; phys slot = slot ^ (row&7), 24-slot stride
    const int tid  = threadIdx.x;
    const int lane = tid & 63;
    const int wv   = tid >> 6;
    const int ln   = lane & 15;
    const int q    = lane >> 4;

    // one-time Wi stage with XOR swizzle (row stride 96 u32 -> bank-neutral;
    // slot^ (row&7) spreads the 16 A-read lanes over 8 bank groups = 2-way, free)
    {
        const int row = tid >> 1;        // 128 rows, 2 threads/row
        const int half = tid & 1;        // 10 slots of 16 B each
        const int rx = row & 7;
        #pragma unroll
        for (int sl = 0; sl < 10; ++sl) {
            int L = half * 10 + sl;      // 0..19
            int P = L ^ rx;              // <= 23, fits 24-slot stride
            *(uint4*)(Wlds + row * 96 + P * 4) = *(const uint4*)(Wp + row * KPU1 + L * 4);
        }
    }
    __syncthreads();

    const int NT = NE / 16;              // 50000 tiles of 16 rows
    const int stride = gridDim.x * 4;
    int s = blockIdx.x * 4 + wv;
    if (s >= NT) return;

    uint4  rA[4];                        // kc0..3 fragment raw (atom, already bf16)
    uint4  rA4;                          // q==0: atom u32 64..67
    float2 b01, b23, b45, b67;           // q==1: bond f0..7 ; q==2: f8..13
    int4   stA;                          // store-row quad

    // ---- prologue: gathers for the first tile
    {
        int p = s * 16 + ln;
        int sr = sidx[p];
        int fr = fidx[p];
        stA = *(const int4*)(pidx + s * 16 + 4 * q);
        const u32* ab = atomBf + (size_t)sr * ATU;
        #pragma unroll
        for (int kc = 0; kc < 4; ++kc)
            rA[kc] = *(const uint4*)(ab + kc * 16 + q * 4);
        if (q == 0) rA4 = *(const uint4*)(ab + 64);
        const float* bp = bond + (size_t)fr * 14;
        if (q == 1) {
            b01 = *(const float2*)(bp + 0); b23 = *(const float2*)(bp + 2);
            b45 = *(const float2*)(bp + 4); b67 = *(const float2*)(bp + 6);
        } else if (q == 2) {
            b01 = *(const float2*)(bp + 8); b23 = *(const float2*)(bp + 10);
            b45 = *(const float2*)(bp + 12);
        }
    }

    while (true) {
        const int sn = s + stride;
        const bool more = sn < NT;       // wave-uniform

        // next tile's index loads (covered by the fragment build below)
        int srB = 0, frB = 0;
        int4 stB;
        if (more) {
            int p = sn * 16 + ln;
            srB = sidx[p];
            frB = fidx[p];
            stB = *(const int4*)(pidx + sn * 16 + 4 * q);
        }

        // build A fragments (consumes raw regs; kc0-3 are pure bitcasts)
        bf16x8 aF[5];
        #pragma unroll
        for (int kc = 0; kc < 4; ++kc) { frag_cast fc; fc.u = rA[kc]; aF[kc] = fc.v; }
        {
            frag_cast f4;
            if (q == 0)      f4.u = rA4;
            else if (q == 1) f4.u = make_uint4(cvt_pk_bf16(b01.x, b01.y), cvt_pk_bf16(b23.x, b23.y),
                                               cvt_pk_bf16(b45.x, b45.y), cvt_pk_bf16(b67.x, b67.y));
            else if (q == 2) f4.u = make_uint4(cvt_pk_bf16(b01.x, b01.y), cvt_pk_bf16(b23.x, b23.y),
                                               cvt_pk_bf16(b45.x, b45.y), 0u);
            else             f4.u = make_uint4(0u, 0u, 0u, 0u);
            aF[4] = f4.v;
        }

        // prefetch next tile's gathers into the freed regs; they stay in
        // flight across the MFMA loop + stores (no VMEM waits below).
        if (more) {
            const u32* ab = atomBf + (size_t)srB * ATU;
            #pragma unroll
            for (int kc = 0; kc < 4; ++kc)
                rA[kc] = *(const uint4*)(ab + kc * 16 + q * 4);
            if (q == 0) rA4 = *(const uint4*)(ab + 64);
            const float* bp = bond + (size_t)frB * 14;
            if (q == 1) {
                b01 = *(const float2*)(bp + 0); b23 = *(const float2*)(bp + 2);
                b45 = *(const float2*)(bp + 4); b67 = *(const float2*)(bp + 6);
            } else if (q == 2) {
                b01 = *(const float2*)(bp + 8); b23 = *(const float2*)(bp + 10);
                b45 = *(const float2*)(bp + 12);
            }
        }

        // MFMA 16x128, K=160; B from LDS only (lgkmcnt -> vmem FIFO untouched).
        u32 zoff = 0;
        asm volatile("" : "+v"(zoff));   // defeat LICM: keep B ds_reads in-loop
        f32x4 acc[8] = {};
        #pragma unroll
        for (int kc = 0; kc < 5; ++kc) {
            const u32* wrow = Wlds + zoff + ln * 96 + (((kc * 4 + q) ^ (ln & 7)) << 2);
            #pragma unroll
            for (int j = 0; j < 8; ++j) {
                bf16x8 b = *(const bf16x8*)(wrow + j * 1536);   // +16 rows * 96 u32
                acc[j] = __builtin_amdgcn_mfma_f32_16x16x32_bf16(aF[kc], b, acc[j], 0, 0, 0);
            }
        }

        // epilogue: full 256-B rows to hout[pidx], 4 consecutive 64-B stores/row
        #pragma unroll
        for (int r = 0; r < 4; ++r) {
            int wrow = (r == 0) ? stA.x : (r == 1) ? stA.y : (r == 2) ? stA.z : stA.w;
            u32* orow = hout + (size_t)wrow * 64;
            #pragma unroll
            for (int a = 0; a < 4; ++a)
                orow[16 * a + ln] = relu2_pk(acc[2 * a][r], acc[2 * a + 1][r]);
        }

        if (!more) break;
        s = sn;
        stA = stB;
    }
}

// ---------------- k_msg: persistent waves, VMEM-free MFMA loop ----------------
// Wh staged once into LDS (XOR-swizzled), B via ds_read_b128 (lgkmcnt), so the
// vmem FIFO holds only prefetch gathers + stores: one wait point/iteration on
// gathers issued a full iteration earlier. 16-row tiles, 12 waves/CU.
// Row p: msg = tmp[sidx[p]] - h[hr], hr = USEIDX ? pidx[p] : p; written back
// to row hr. Row ownership is a bijection -> prefetch never races stores.
template<bool USEIDX>
__global__ __launch_bounds__(256, 3)
void k_msg_t(const int* __restrict__ sidx, const int* __restrict__ pidx,
             const u32* __restrict__ Wp, const u32* __restrict__ tmp,
             u32* __restrict__ h)
{
    __shared__ u32 Wlds[128 * 64];   // 32 KB; slot phys = slot ^ (row&15)
    const int tid  = threadIdx.x;
    const int lane = tid & 63;
    const int wv   = tid >> 6;
    const int ln   = lane & 15;
    const int q    = lane >> 4;

    // one-time Wh stage with XOR swizzle (kills 16-way conflict of 256-B rows)
    {
        const int row = tid >> 1;        // 128 rows, 2 threads/row
        const int half = tid & 1;        // 8 slots of 16 B each
        const int rx = row & 15;
        #pragma unroll
        for (int sl = 0; sl < 8; ++sl) {
            int L = half * 8 + sl;
            int P = L ^ rx;
            *(uint4*)(Wlds + row * 64 + P * 4) = *(const uint4*)(Wp + row * 64 + L * 4);
        }
    }
    __syncthreads();

    const int NT = NE / 16;              // 50000 tiles of 16 rows
    const int stride = gridDim.x * 4;
    int s = blockIdx.x * 4 + wv;
    if (s >= NT) return;

    int4  stA;                           // store-row quad (USEIDX only)
    uint4 tv[4], hv[4];                  // raw gathered operands

    // ---- prologue: gathers for the first tile
    {
        int p = s * 16 + ln;
        int sr = sidx[p];
        int hr = USEIDX ? pidx[p] : p;
        if (USEIDX) stA = *(const int4*)(pidx + s * 16 + 4 * q);
        const u32* tb = tmp + (size_t)sr * 64 + q * 4;
        const u32* hb = h   + (size_t)hr * 64 + q * 4;
        #pragma unroll
        for (int kc = 0; kc < 4; ++kc) {
            tv[kc] = *(const uint4*)(tb + kc * 16);
            hv[kc] = *(const uint4*)(hb + kc * 16);
        }
    }

    while (true) {
        const int sn = s + stride;
        const bool more = sn < NT;       // wave-uniform

        // next tile's index loads (covered by the convert below)
        int srB = 0, hrB = 0;
        int4 stB;
        if (more) {
            int p = sn * 16 + ln;
            srB = sidx[p];
            hrB = USEIDX ? pidx[p] : p;
            if (USEIDX) stB = *(const int4*)(pidx + sn * 16 + 4 * q);
        }

        // convert current raw -> A fragments (frees tv/hv)
        bf16x8 aF[4];
        #pragma unroll
        for (int kc = 0; kc < 4; ++kc) {
            frag_cast fc;
            fc.u.x = sub2_pk(tv[kc].x, hv[kc].x);
            fc.u.y = sub2_pk(tv[kc].y, hv[kc].y);
            fc.u.z = sub2_pk(tv[kc].z, hv[kc].z);
            fc.u.w = sub2_pk(tv[kc].w, hv[kc].w);
            aF[kc] = fc.v;
        }

        // prefetch next tile's gathers into the freed regs; they stay in
        // flight across the MFMA loop + stores (no VMEM waits below).
        if (more) {
            const u32* tb = tmp + (size_t)srB * 64 + q * 4;
            const u32* hb = h   + (size_t)hrB * 64 + q * 4;
            #pragma unroll
            for (int kc = 0; kc < 4; ++kc) {
                tv[kc] = *(const uint4*)(tb + kc * 16);
                hv[kc] = *(const uint4*)(hb + kc * 16);
            }
        }

        // MFMA 16x128, K=128; B from LDS only (lgkmcnt -> vmem FIFO untouched).
        u32 zoff = 0;
        asm volatile("" : "+v"(zoff));   // defeat LICM: keep B ds_reads in-loop
        f32x4 acc[8] = {};
        #pragma unroll
        for (int kc = 0; kc < 4; ++kc) {
            const u32* wrow = Wlds + zoff + ln * 64 + (((kc * 4 + q) ^ ln) << 2);
            #pragma unroll
            for (int j = 0; j < 8; ++j) {
                bf16x8 b = *(const bf16x8*)(wrow + j * 1024);
                acc[j] = __builtin_amdgcn_mfma_f32_16x16x32_bf16(aF[kc], b, acc[j], 0, 0, 0);
            }
        }

        // epilogue: full 256-B rows, 4 consecutive 64-B segment stores per row
        #pragma unroll
        for (int r = 0; r < 4; ++r) {
            int wrow = USEIDX
                ? ((r == 0) ? stA.x : (r == 1) ? stA.y : (r == 2) ? stA.z : stA.w)
                : (s * 16 + 4 * q + r);
            u32* orow = h + (size_t)wrow * 64;
            #pragma unroll
            for (int a = 0; a < 4; ++a)
                orow[16 * a + ln] = relu2_pk(acc[2 * a][r], acc[2 * a + 1][r]);
        }

        if (!more) break;
        s = sn;
        if (USEIDX) stA = stB;
    }
}

// ---------------- k_out: 64-node tiles, 4 waves (32x64 each) ----------------
__global__ __launch_bounds__(256, 4)
void k_out(const u32* __restrict__ atomBf, const u32* __restrict__ Wp,
           const u32* __restrict__ tmp, float* __restrict__ out)
{
    __shared__ u32 As[64 * KPU3];   // 37888 B -> 4 blocks/CU
    const int tid = threadIdx.x;
    const int lane = tid & 63;
    const int wv = tid >> 6;
    const int ln = lane & 15;
    const int q  = lane >> 4;
    const int rowBase = 32 * (wv >> 1);
    const int colBase = 64 * (wv & 1);
    const int ntiles = (NN + 63) / 64;

    const int srow = tid >> 2;
    const int qt = tid & 3;
    const uint4 z4 = make_uint4(0u, 0u, 0u, 0u);

    for (int tile = blockIdx.x; tile < ntiles; tile += gridDim.x) {
        const int n0 = tile * 64;
        {
            int n = n0 + srow;
            bool ok = n < NN;
            const u32* ap = atomBf + (size_t)n * ATU;
            const u32* tp = tmp + (size_t)n * 64;
            u32* dr = As + srow * KPU3;
            if (qt == 0) {
                #pragma unroll
                for (int j = 0; j < 9; ++j)
                    *(uint4*)(dr + 4 * j) = ok ? *(const uint4*)(ap + 4 * j) : z4;
            } else if (qt == 1) {
                #pragma unroll
                for (int j = 9; j < 17; ++j)
                    *(uint4*)(dr + 4 * j) = ok ? *(const uint4*)(ap + 4 * j) : z4;
            } else if (qt == 2) {
                #pragma unroll
                for (int j = 0; j < 8; ++j)
                    *(uint4*)(dr + 68 + 4 * j) = ok ? *(const uint4*)(tp + 4 * j) : z4;
                *(uint4*)(dr + 132) = z4;
            } else {
                #pragma unroll
                for (int j = 8; j < 16; ++j)
                    *(uint4*)(dr + 68 + 4 * j) = ok ? *(const uint4*)(tp + 4 * j) : z4;
                *(uint4*)(dr + 136) = z4;
                *(uint4*)(dr + 140) = z4;
            }
        }
        __syncthreads();

        f32x4 acc[2][4] = {};
        #pragma unroll
        for (int kc = 0; kc < KC3; ++kc) {
            const int kHalf = kc * 16 + q * 4;
            bf16x8 a[2], b[4];
            #pragma unroll
            for (int i = 0; i < 2; ++i)
                a[i] = *(const bf16x8*)(&As[(rowBase + 16 * i + ln) * KPU3 + kHalf]);
            #pragma unroll
            for (int j = 0; j < 4; ++j)
                b[j] = *(const bf16x8*)(Wp + (colBase + 16 * j + ln) * KPU3 + kHalf);
            #pragma unroll
            for (int i = 0; i < 2; ++i)
                #pragma unroll
                for (int j = 0; j < 4; ++j)
                    acc[i][j] = __builtin_amdgcn_mfma_f32_16x16x32_bf16(a[i], b[j], acc[i][j], 0, 0, 0);
        }
        __syncthreads();

        #pragma unroll
        for (int i = 0; i < 2; ++i) {
            #pragma unroll
            for (int r = 0; r < 4; ++r) {
                int n = n0 + rowBase + 16 * i + q * 4 + r;
                if (n < NN) {
                    float2* orow = (float2*)(out + (size_t)n * HID);
                    float2 v01, v23;
                    v01.x = relu(acc[i][0][r]); v01.y = relu(acc[i][1][r]);
                    v23.x = relu(acc[i][2][r]); v23.y = relu(acc[i][3][r]);
                    orow[(colBase >> 1) + ln]      = v01;
                    orow[(colBase >> 1) + 16 + ln] = v23;
                }
            }
        }
    }
}

// ---------------- launch ----------------

extern "C" void kernel_launch(void* const* d_in, const int* in_sizes, int n_in,
                              void* d_out, int out_size, void* d_ws, size_t ws_size,
                              hipStream_t stream) {
    const float* atom = (const float*)d_in[0];   // [50000][133]
    const float* bond = (const float*)d_in[1];   // [800000][14]
    const float* Wi   = (const float*)d_in[2];   // [128][147]
    const float* Wh   = (const float*)d_in[3];   // [128][128]
    const float* Wo   = (const float*)d_in[4];   // [128][261]
    const int*   src  = (const int*)d_in[5]; (void)src;
    const int*   dst  = (const int*)d_in[6];
    const int*   rev  = (const int*)d_in[7];
    float* out = (float*)d_out;

    char* ws = (char*)d_ws;
    size_t off = 0;
    auto take = [&](size_t bytes) { char* p = ws + off; off = (off + bytes + 255) & ~(size_t)255; return p; };
    u32* hbuf   = (u32*)take((size_t)NE * 64 * 4);     // 204.8 MB
    u32* tmp    = (u32*)take((size_t)NN * 64 * 4);     // 12.8 MB
    u32* atomBf = (u32*)take((size_t)NN * ATU * 4);    // 13.6 MB
    int* fidx   = (int*)take((size_t)NE * 4);
    int* sidx   = (int*)take((size_t)NE * 4);
    int* posOf  = (int*)take((size_t)NE * 4);
    int* pidx   = (int*)take((size_t)NE * 4);
    int* cnt    = (int*)take((size_t)NN * 4);
    int* lexc   = (int*)take((size_t)NN * 4);
    int* rowptr = (int*)take((size_t)(NN + 1) * 4);
    int* cursor = (int*)take((size_t)NN * 4);
    int* chunkSum = (int*)take(256 * 4);
    int* chunkOff = (int*)take(256 * 4);
    u32* WiP = (u32*)take(128 * KPU1 * 4);
    u32* WhP = (u32*)take(128 * WHU * 4);
    u32* WoP = (u32*)take(128 * KPU3 * 4);
    // total ~245 MB

    cvt_atom<<<2048, 256, 0, stream>>>(atom, atomBf);
    cvt_w<<<48, 256, 0, stream>>>(Wi, WiP, 147, KPU1, 133, 136, 14);
    cvt_w<<<32, 256, 0, stream>>>(Wh, WhP, 128, WHU, 128, 1 << 20, 0);
    cvt_w<<<80, 256, 0, stream>>>(Wo, WoP, 261, KPU3, 133, 136, 128);

    hipMemsetAsync(cnt, 0, (size_t)NN * 4, stream);
    hist<<<1024, 256, 0, stream>>>(dst, cnt);
    scan1<<<NCH, 256, 0, stream>>>(cnt, lexc, chunkSum);
    scan2<<<1, 256, 0, stream>>>(chunkSum, chunkOff);
    scan3<<<NCH, 256, 0, stream>>>(lexc, chunkOff, rowptr, cursor);
    scatter<<<1024, 256, 0, stream>>>(dst, rev, cursor, fidx, sidx, posOf);
    pidx_build<<<1024, 256, 0, stream>>>(fidx, posOf, pidx);

    k_init<<<768, 256, 0, stream>>>(atomBf, bond, fidx, sidx, pidx, WiP, hbuf);   // e-layout
    segsum_t<false><<<2048, 256, 0, stream>>>(rowptr, nullptr, hbuf, tmp);        // sequential
    k_msg_t<false><<<768, 256, 0, stream>>>(sidx, pidx, WhP, tmp, hbuf);          // all-stream -> f-layout
    segsum_t<true><<<2048, 256, 0, stream>>>(rowptr, pidx, hbuf, tmp);            // gather
    k_msg_t<true><<<768, 256, 0, stream>>>(sidx, pidx, WhP, tmp, hbuf);           // random rows -> e-layout
    segsum_t<false><<<2048, 256, 0, stream>>>(rowptr, nullptr, hbuf, tmp);        // sequential
    k_out<<<782, 256, 0, stream>>>(atomBf, WoP, tmp, out);
}